// Round 5
// baseline (164.081 us; speedup 1.0000x reference)
//
#include <hip/hip_runtime.h>

#define BLOCK   256                 // 4 waves
#define RELEM   512                 // elems per wave-region (64 lanes * 8)
#define WREG    4                   // contiguous regions per wave
#define BREG    (4 * WREG)          // regions per block
#define STAGES  3                   // software-pipeline depth

// Branch-free BCE matching jnp: -(t*clip(log p,-100) + (1-t)*clip(log1p(-p),-100))
// log1p(-p) -> __logf(1-p): abs err ~6e-8, far inside the 2e3 threshold.
__device__ __forceinline__ float bce_elem(float p, float t) {
    float lp  = fmaxf(__logf(p), -100.0f);        // v_log_f32(0) = -inf -> clamped
    float l1p = fmaxf(__logf(1.0f - p), -100.0f);
    return -__builtin_fmaf(t, lp - l1p, l1p);     // -(t*(lp-l1p) + l1p)
}

// Wave-collective: reduce (b,c) across 64 lanes, lane0 atomics into seg s.
__device__ __forceinline__ void wave_flush(int s, float b, float c,
    float* __restrict__ seg_bce, float* __restrict__ seg_cnt, int lane)
{
    #pragma unroll
    for (int o = 32; o > 0; o >>= 1) {
        b += __shfl_xor(b, o);
        c += __shfl_xor(c, o);
    }
    if (lane == 0 && s >= 0) {
        atomicAdd(&seg_bce[s], b);
        atomicAdd(&seg_cnt[s], c);
    }
}

struct Stage {                      // 26 VGPRs of staged data
    float4 p0, p1, t0, t1;
    int4   m0, m1;
    int    sF, sL;                  // batch[rb], batch[rb+511] (same-addr broadcast)
};

__device__ __forceinline__ void stage_load(Stage& s,
    const float* __restrict__ pred, const float* __restrict__ tgt,
    const int* __restrict__ batch, const int* __restrict__ mask,
    long rb, int lane)
{
    // segment endpoints: all lanes hit the same address -> 1 line + broadcast
    s.sF = batch[rb];
    s.sL = batch[rb + RELEM - 1];
    const float4* p4 = reinterpret_cast<const float4*>(pred + rb);
    const float4* t4 = reinterpret_cast<const float4*>(tgt + rb);
    const int4*   m4 = reinterpret_cast<const int4*>(mask + rb);
    s.p0 = p4[lane]; s.p1 = p4[64 + lane];
    s.t0 = t4[lane]; s.t1 = t4[64 + lane];
    s.m0 = m4[lane]; s.m1 = m4[64 + lane];
}

__device__ __forceinline__ void consume(const Stage& s, long rb, int lane,
    int& runSeg, float& accb, float& accc,
    const int* __restrict__ batch,
    float* __restrict__ seg_bce, float* __restrict__ seg_cnt)
{
    int segF = __builtin_amdgcn_readfirstlane(s.sF);
    int segL = __builtin_amdgcn_readfirstlane(s.sL);

    float pv[8] = {s.p0.x, s.p0.y, s.p0.z, s.p0.w, s.p1.x, s.p1.y, s.p1.z, s.p1.w};
    float tv[8] = {s.t0.x, s.t0.y, s.t0.z, s.t0.w, s.t1.x, s.t1.y, s.t1.z, s.t1.w};
    int   mv[8] = {s.m0.x, s.m0.y, s.m0.z, s.m0.w, s.m1.x, s.m1.y, s.m1.z, s.m1.w};

    if (segF == segL) {
        // HOT (~87%): whole region one segment (batch sorted). Straight-line.
        if (runSeg != segF) {
            if (runSeg >= 0) wave_flush(runSeg, accb, accc, seg_bce, seg_cnt, lane);
            accb = 0.0f; accc = 0.0f; runSeg = segF;
        }
        #pragma unroll
        for (int j = 0; j < 8; ++j) {
            float mf = (float)mv[j];
            accb += bce_elem(pv[j] * mf, tv[j]);
            accc += mf;
        }
    } else {
        // COLD (~13%): boundary region. Reload batch int4s (L1/L2-hot).
        if (runSeg >= 0) wave_flush(runSeg, accb, accc, seg_bce, seg_cnt, lane);
        accb = 0.0f; accc = 0.0f; runSeg = -1;
        const int4* b4 = reinterpret_cast<const int4*>(batch + rb);
        int4 s0 = b4[lane], s1 = b4[64 + lane];
        int sv[8] = {s0.x, s0.y, s0.z, s0.w, s1.x, s1.y, s1.z, s1.w};
        float bv[8], cv[8];
        #pragma unroll
        for (int j = 0; j < 8; ++j) {
            float mf = (float)mv[j];
            bv[j] = bce_elem(pv[j] * mf, tv[j]);
            cv[j] = mf;
        }
        for (int g = segF; g <= segL; ++g) {
            float pb = 0.0f, pc = 0.0f;
            #pragma unroll
            for (int j = 0; j < 8; ++j)
                if (sv[j] == g) { pb += bv[j]; pc += cv[j]; }
            wave_flush(g, pb, pc, seg_bce, seg_cnt, lane);
        }
    }
}

__global__ __launch_bounds__(BLOCK) void seg_bce_kernel(
    const float* __restrict__ pred, const float* __restrict__ tgt,
    const int* __restrict__ batch, const int* __restrict__ mask,
    float* __restrict__ seg_bce, float* __restrict__ seg_cnt, int n)
{
    const int wave = threadIdx.x >> 6;
    const int lane = threadIdx.x & 63;
    const int nreg = n >> 9;                              // full 512-elem regions
    const long r0  = (long)blockIdx.x * BREG + (long)wave * WREG;

    int   runSeg = -1;
    float accb = 0.0f, accc = 0.0f;
    Stage st[STAGES];

    // Prologue: fill pipeline with stages 0..STAGES-2.
    #pragma unroll
    for (int k = 0; k < STAGES - 1; ++k)
        if (r0 + k < nreg)
            stage_load(st[k], pred, tgt, batch, mask, (r0 + k) * RELEM, lane);

    #pragma unroll
    for (int i = 0; i < WREG; ++i) {
        // Prefetch stage i+STAGES-1, then fence: loads may NOT sink below.
        long rp = r0 + i + (STAGES - 1);
        if (i + (STAGES - 1) < WREG && rp < nreg)
            stage_load(st[(i + STAGES - 1) % STAGES], pred, tgt, batch, mask,
                       rp * RELEM, lane);
        __builtin_amdgcn_sched_barrier(0);
        long r = r0 + i;
        if (r < nreg)
            consume(st[i % STAGES], r * RELEM, lane,
                    runSeg, accb, accc, batch, seg_bce, seg_cnt);
    }
    if (runSeg >= 0) wave_flush(runSeg, accb, accc, seg_bce, seg_cnt, lane);

    // Element tail (n % 512) — empty for N=8M, kept for generality.
    if (blockIdx.x == 0 && wave == 0) {
        for (long idx = (long)nreg * RELEM + lane; idx < n; idx += 64) {
            float mf = (float)mask[idx];
            float b  = bce_elem(pred[idx] * mf, tgt[idx]);
            atomicAdd(&seg_bce[batch[idx]], b);
            atomicAdd(&seg_cnt[batch[idx]], mf);
        }
    }
}

__global__ __launch_bounds__(256) void finalize_kernel(
    const float* __restrict__ seg_bce, const float* __restrict__ seg_cnt,
    const float* __restrict__ sat_pred, const float* __restrict__ sat_tgt,
    float* __restrict__ out, int Bseg)
{
    const float l1_over_b = (1.0f / 50.0f) / (float)Bseg;   // mean * L1
    float local = 0.0f;
    for (int i = threadIdx.x; i < Bseg; i += blockDim.x) {
        float c = seg_cnt[i];
        if (c > 0.0f) local += seg_bce[i] / fmaxf(c, 1.0f);
        local += bce_elem(sat_pred[i], sat_tgt[i]) * l1_over_b;
    }
    #pragma unroll
    for (int o = 32; o > 0; o >>= 1) local += __shfl_xor(local, o);
    __shared__ float ws[4];
    if ((threadIdx.x & 63) == 0) ws[threadIdx.x >> 6] = local;
    __syncthreads();
    if (threadIdx.x == 0) out[0] = ws[0] + ws[1] + ws[2] + ws[3];
}

extern "C" void kernel_launch(void* const* d_in, const int* in_sizes, int n_in,
                              void* d_out, int out_size, void* d_ws, size_t ws_size,
                              hipStream_t stream) {
    const float* y_mus_pred = (const float*)d_in[0];
    const float* y_mus      = (const float*)d_in[1];
    const float* y_sat_pred = (const float*)d_in[2];
    const float* y_sat      = (const float*)d_in[3];
    const int*   batch      = (const int*)d_in[4];
    const int*   mask       = (const int*)d_in[5];

    const int n    = in_sizes[0];
    const int Bseg = in_sizes[2];

    float* seg_bce = (float*)d_ws;
    float* seg_cnt = seg_bce + Bseg;

    // d_ws is re-poisoned (0xAA) before every launch -> zero the accumulators.
    hipMemsetAsync(d_ws, 0, 2 * (size_t)Bseg * sizeof(float), stream);

    const int nreg    = n >> 9;
    const int nblocks = (nreg + BREG - 1) / BREG;     // 977 at N=8M
    seg_bce_kernel<<<nblocks, BLOCK, 0, stream>>>(
        y_mus_pred, y_mus, batch, mask, seg_bce, seg_cnt, n);
    finalize_kernel<<<1, 256, 0, stream>>>(
        seg_bce, seg_cnt, y_sat_pred, y_sat, (float*)d_out, Bseg);
}

// Round 6
// 157.148 us; speedup vs baseline: 1.0441x; 1.0441x over previous
//
#include <hip/hip_runtime.h>

#define BLOCK 256

// Branch-free BCE matching jnp: -(t*clip(log p,-100) + (1-t)*clip(log1p(-p),-100))
// log1p(-p) -> __logf(1-p): abs err ~6e-8, far inside the 2e3 threshold.
__device__ __forceinline__ float bce_elem(float p, float t) {
    float lp  = fmaxf(__logf(p), -100.0f);        // v_log_f32(0) = -inf -> clamped
    float l1p = fmaxf(__logf(1.0f - p), -100.0f);
    return -__builtin_fmaf(t, lp - l1p, l1p);     // -(t*(lp-l1p) + l1p)
}

// first index i in [0,n) with a[i] >= v  (a sorted ascending)
__device__ __forceinline__ int lower_bound(const int* __restrict__ a, int n, int v) {
    int lo = 0, hi = n;
    while (lo < hi) {
        int mid = (int)(((unsigned)lo + (unsigned)hi) >> 1);
        if (a[mid] < v) lo = mid + 1; else hi = mid;
    }
    return lo;
}

// One block per segment. Hot loop is a pure float4 stride loop: no branches,
// no cross-lane, no atomics -- the shape this chip streams at 5-6 TB/s.
__global__ __launch_bounds__(BLOCK) void seg_kernel(
    const float* __restrict__ pred, const float* __restrict__ tgt,
    const int* __restrict__ batch, const int* __restrict__ mask,
    const float* __restrict__ sat_pred, const float* __restrict__ sat_tgt,
    float* __restrict__ per_graph, int n, int Bseg)
{
    const int b   = blockIdx.x;
    const int tid = threadIdx.x;

    __shared__ int sh_lo, sh_hi;
    if (tid == 0) sh_lo = lower_bound(batch, n, b);
    if (tid == 1) sh_hi = lower_bound(batch, n, b + 1);
    __syncthreads();
    const int lo = sh_lo, hi = sh_hi;          // this block owns batch range [lo,hi)

    float accb = 0.0f, accc = 0.0f;

    int a0 = (lo + 3) & ~3;                    // first 16B-aligned element
    if (a0 > hi) a0 = hi;
    const int nvec = (hi - a0) >> 2;
    const int a1   = a0 + (nvec << 2);

    // scalar head (<=3 elems)
    for (int i = lo + tid; i < a0; i += BLOCK) {
        float mf = (float)mask[i];
        accb += bce_elem(pred[i] * mf, tgt[i]);
        accc += mf;
    }
    // vector body: 3 coalesced float4 streams, ~4 iterations/thread
    const float4* p4 = reinterpret_cast<const float4*>(pred) + (a0 >> 2);
    const float4* t4 = reinterpret_cast<const float4*>(tgt)  + (a0 >> 2);
    const int4*   m4 = reinterpret_cast<const int4*>(mask)   + (a0 >> 2);
    for (int i = tid; i < nvec; i += BLOCK) {
        float4 p = p4[i];
        float4 t = t4[i];
        int4   m = m4[i];
        float m0 = (float)m.x, m1 = (float)m.y, m2 = (float)m.z, m3 = (float)m.w;
        accb += bce_elem(p.x * m0, t.x);  accc += m0;
        accb += bce_elem(p.y * m1, t.y);  accc += m1;
        accb += bce_elem(p.z * m2, t.z);  accc += m2;
        accb += bce_elem(p.w * m3, t.w);  accc += m3;
    }
    // scalar tail (<=3 elems)
    for (int i = a1 + tid; i < hi; i += BLOCK) {
        float mf = (float)mask[i];
        accb += bce_elem(pred[i] * mf, tgt[i]);
        accc += mf;
    }

    // block reduction: wave shfl -> LDS -> thread 0
    #pragma unroll
    for (int o = 32; o > 0; o >>= 1) {
        accb += __shfl_xor(accb, o);
        accc += __shfl_xor(accc, o);
    }
    __shared__ float wb[4], wc[4];
    if ((tid & 63) == 0) { wb[tid >> 6] = accb; wc[tid >> 6] = accc; }
    __syncthreads();
    if (tid == 0) {
        float sb = wb[0] + wb[1] + wb[2] + wb[3];
        float sc = wc[0] + wc[1] + wc[2] + wc[3];
        float pg = (sc > 0.0f) ? sb / fmaxf(sc, 1.0f) : 0.0f;
        // fold this graph's share of the sat-BCE mean*L1 term; every b covered once
        pg += bce_elem(sat_pred[b], sat_tgt[b]) * ((1.0f / 50.0f) / (float)Bseg);
        per_graph[b] = pg;                      // plain store: no atomics anywhere
    }
}

__global__ __launch_bounds__(256) void sum_kernel(
    const float* __restrict__ per_graph, float* __restrict__ out, int Bseg)
{
    float local = 0.0f;
    for (int i = threadIdx.x; i < Bseg; i += 256) local += per_graph[i];
    #pragma unroll
    for (int o = 32; o > 0; o >>= 1) local += __shfl_xor(local, o);
    __shared__ float ws[4];
    if ((threadIdx.x & 63) == 0) ws[threadIdx.x >> 6] = local;
    __syncthreads();
    if (threadIdx.x == 0) out[0] = ws[0] + ws[1] + ws[2] + ws[3];
}

extern "C" void kernel_launch(void* const* d_in, const int* in_sizes, int n_in,
                              void* d_out, int out_size, void* d_ws, size_t ws_size,
                              hipStream_t stream) {
    const float* y_mus_pred = (const float*)d_in[0];
    const float* y_mus      = (const float*)d_in[1];
    const float* y_sat_pred = (const float*)d_in[2];
    const float* y_sat      = (const float*)d_in[3];
    const int*   batch      = (const int*)d_in[4];
    const int*   mask       = (const int*)d_in[5];

    const int n    = in_sizes[0];
    const int Bseg = in_sizes[2];

    float* per_graph = (float*)d_ws;   // Bseg floats; every slot written each launch

    seg_kernel<<<Bseg, BLOCK, 0, stream>>>(
        y_mus_pred, y_mus, batch, mask, y_sat_pred, y_sat, per_graph, n, Bseg);
    sum_kernel<<<1, 256, 0, stream>>>(per_graph, (float*)d_out, Bseg);
}